// Round 10
// baseline (469.585 us; speedup 1.0000x reference)
//
#include <hip/hip_runtime.h>

// ---------------- constants ----------------
#define NTOP   4096
#define SORTN  8192
#define CONF_T 0.5f
#define IOU_T  0.6f

// ws layout (bytes)
#define HIST_OFF   0          // 2048 * u32 = 8 KB
#define CUT_OFF    8192       // int
#define CNT_OFF    8196       // u32
#define COMP_OFF   16384      // 8192 * u64 = 64 KB  (zeroed)
#define MEMSET_BYTES 81920    // covers hist+cut+cnt+comp
#define KEYS_OFF   131072     // 200000 * u64 = 1.6 MB
#define TB_OFF     2097152    // 4096 * float4 = 64 KB
#define TC_OFF     2162688    // 4096 * float  = 16 KB
#define VALID_OFF  2179072    // 64 * u64
#define KEEP_OFF   2179584    // 64 * u64
#define MASK_OFF   4194304    // 4096*64*u64 = 2 MB

typedef unsigned long long u64;
typedef unsigned int u32;

// async global->LDS copy, 16B per lane per issue (1 KB per wave-instruction)
__device__ __forceinline__ void gload_lds16(const void* g, void* l) {
    __builtin_amdgcn_global_load_lds(
        (const __attribute__((address_space(1))) unsigned int*)g,
        (__attribute__((address_space(3))) unsigned int*)l, 16, 0, 0);
}

// K1: build keys + histogram of top-20 bits of score (valid only)
__global__ void k_keys(const float* __restrict__ confs, u64* __restrict__ keys,
                       u32* __restrict__ hist, int n) {
    int i = blockIdx.x * 256 + threadIdx.x;
    if (i >= n) return;
    float s = confs[i];
    if (s >= CONF_T) {
        u32 u = __float_as_uint(s);              // positive -> bits monotone
        keys[i] = ((u64)u << 32) | (u32)(~i);    // tie: lower index wins
        int bin = (int)(u >> 12) - 0x3F000;      // [0.5,1) -> [0,2047]
        bin = bin < 0 ? 0 : (bin > 2047 ? 2047 : bin);
        atomicAdd(&hist[bin], 1u);
    } else {
        keys[i] = 0ull;
    }
}

// K2: find cut bucket (largest b with suffix-count >= NTOP), single block
__global__ __launch_bounds__(256) void k_findcut(const u32* __restrict__ hist,
                                                 int* __restrict__ cut) {
    __shared__ u32 ch[256];
    int t = threadIdx.x;
    u32 h[8]; u32 s = 0;
#pragma unroll
    for (int k = 0; k < 8; ++k) { h[k] = hist[t * 8 + k]; s += h[k]; }
    ch[t] = s;
    __syncthreads();
    // inclusive suffix scan of chunk sums
    for (int off = 1; off < 256; off <<= 1) {
        u32 v = ch[t];
        u32 add = (t + off < 256) ? ch[t + off] : 0u;
        __syncthreads();
        ch[t] = v + add;
        __syncthreads();
    }
    u32 incl = ch[t];            // sum over bins >= t*8
    u32 above = incl - s;        // sum over bins >= (t+1)*8
    if (above < NTOP && incl >= NTOP) {
        u32 cum = above; int c = 0;
        for (int k = 7; k >= 0; --k) {
            cum += h[k];
            if (cum >= NTOP) { c = t * 8 + k; break; }
        }
        *cut = c;
    }
    if (t == 0 && ch[0] < NTOP) *cut = 0;   // fewer than NTOP valid: take all
}

// K3: compact candidates with bucket >= cut
__global__ void k_compact(const u64* __restrict__ keys, const int* __restrict__ cut,
                          u64* __restrict__ comp, u32* __restrict__ counter, int n) {
    int i = blockIdx.x * 256 + threadIdx.x;
    if (i >= n) return;
    u64 key = keys[i];
    if (!key) return;
    int bin = (int)(u32)(key >> 44) - 0x3F000;
    bin = bin < 0 ? 0 : (bin > 2047 ? 2047 : bin);
    if (bin >= *cut) {
        u32 p = atomicAdd(counter, 1u);
        if (p < SORTN) comp[p] = key;
    }
}

// K4: bitonic sort SORTN u64 keys descending, single block, 64KB LDS.
// Epilogue (fused, was k_gather): gather top boxes/scores, build valid bitmask.
__global__ __launch_bounds__(1024) void k_sort(const u64* __restrict__ comp,
                                               const float4* __restrict__ boxes,
                                               float4* __restrict__ tb,
                                               float* __restrict__ tc,
                                               u64* __restrict__ validmask) {
    __shared__ u64 sm[SORTN];
    int t = threadIdx.x;
    for (int i = t; i < SORTN; i += 1024) sm[i] = comp[i];
    __syncthreads();
    for (int k = 2; k <= SORTN; k <<= 1) {
        for (int j = k >> 1; j > 0; j >>= 1) {
            for (int i = t; i < SORTN; i += 1024) {
                int ixj = i ^ j;
                if (ixj > i) {
                    u64 a = sm[i], b = sm[ixj];
                    bool sw = ((i & k) == 0) ? (a < b) : (a > b);  // descending
                    if (sw) { sm[i] = b; sm[ixj] = a; }
                }
            }
            __syncthreads();
        }
    }
    // fused gather: first NTOP sorted keys -> boxes/scores/valid bitmask
    for (int base = 0; base < NTOP; base += 1024) {
        int k = base + t;
        u64 key = sm[k];
        float score = __uint_as_float((u32)(key >> 32));
        bool valid = (key != 0ull) && (score >= CONF_T);
        float4 b = make_float4(0.f, 0.f, 0.f, 0.f);
        if (valid) {
            u32 idx = ~(u32)(key & 0xFFFFFFFFull);
            b = boxes[idx];
        }
        tb[k] = b;
        tc[k] = score;
        u64 bal = __ballot(valid);
        if ((t & 63) == 0) validmask[k >> 6] = bal;
    }
}

// K6: suppression bitmask matrix: mask[row][w] bit j = iou(row, w*64+j) > T
__global__ __launch_bounds__(256) void k_mask(const float4* __restrict__ tb,
                                              u64* __restrict__ mask) {
    __shared__ float4 cb[64];
    __shared__ float  ca[64];
    int w = blockIdx.x;           // word 0..63
    int t = threadIdx.x;
    if (t < 64) {
        float4 b = tb[w * 64 + t];
        cb[t] = b;
        ca[t] = fmaxf(b.z - b.x, 0.f) * fmaxf(b.w - b.y, 0.f);
    }
    __syncthreads();
    int row = blockIdx.y * 256 + t;
    float4 rb = tb[row];
    float ra = fmaxf(rb.z - rb.x, 0.f) * fmaxf(rb.w - rb.y, 0.f);
    u64 m = 0;
#pragma unroll 8
    for (int j = 0; j < 64; ++j) {
        float4 c = cb[j];
        float lx = fmaxf(rb.x, c.x), ly = fmaxf(rb.y, c.y);
        float rx = fminf(rb.z, c.z), ry = fminf(rb.w, c.w);
        float iw = fmaxf(rx - lx, 0.f), ih = fmaxf(ry - ly, 0.f);
        float inter = iw * ih;
        float iou = inter / (ra + ca[j] - inter + 1e-9f);
        if (iou > IOU_T) m |= (1ull << j);
    }
    mask[(size_t)row * 64 + w] = m;
}

// ---- K7 consumer macros: batched LDS reads + scalar-chain step (r8/r9-
// validated bit logic, unchanged). All rows/bits are compile-time literals. ----
#define RD(p, base) \
    p##0 = Bp[(base + 0) * 64 + lane]; p##1 = Bp[(base + 1) * 64 + lane]; \
    p##2 = Bp[(base + 2) * 64 + lane]; p##3 = Bp[(base + 3) * 64 + lane]; \
    p##4 = Bp[(base + 4) * 64 + lane]; p##5 = Bp[(base + 5) * 64 + lane]; \
    p##6 = Bp[(base + 6) * 64 + lane]; p##7 = Bp[(base + 7) * 64 + lane];

#define ST(rv, bit) { \
    u32 dlo = (u32)__builtin_amdgcn_readlane((int)(u32)(rv), w); \
    u32 dhi = (u32)__builtin_amdgcn_readlane((int)(u32)((rv) >> 32), w); \
    u64 dwv = ((u64)dhi << 32) | dlo;   /* diagonal word mask[row][w] */ \
    bool is_keep = ((cur >> (bit)) & 1ull) == 0ull; \
    u64 mm = is_keep ? ~0ull : 0ull;    /* uniform -> s_cselect_b64 */ \
    cur |= dwv & mm;                    /* scalar chain */ \
    mysup |= (rv) & mm;                 /* vector accumulate */ \
    blockkeep |= is_keep ? (1ull << (bit)) : 0ull; }

#define PR(p, base) \
    ST(p##0, base + 0) ST(p##1, base + 1) ST(p##2, base + 2) ST(p##3, base + 3) \
    ST(p##4, base + 4) ST(p##5, base + 5) ST(p##6, base + 6) ST(p##7, base + 7)

// K7: serial greedy NMS — producer/consumer, one 256-thread block.
// r9 post-mortem: the producer's load->ds_write loop serialized into ~11 HBM
// round-trips per block (~8.2K cy — measured 8.4K). Fix: async
// global_load_lds staging — no VGPR round-trip, all ~11 copies per wave in
// flight at once, single implicit vmcnt(0) drain at the barrier. Consumer
// (wave 0) scans from the LDS double-buffer, unchanged.
__global__ __launch_bounds__(256, 1) void k_nms(const u64* __restrict__ mask,
                                                const u64* __restrict__ validmask,
                                                u64* __restrict__ keep) {
    __shared__ u64 buf[2][64 * 64];     // 2 x 32 KB (one 64-row block each)
    int tid = threadIdx.x;
    int lane = tid & 63;
    int wid = tid >> 6;

    // prologue: stage block 0 into buf[0] (all 4 waves, async)
    {
        const char* src = (const char*)mask;
        char* dst = (char*)&buf[0][0];
        for (int c = wid; c < 32; c += 4)            // c uniform per wave
            gload_lds16(src + c * 1024 + lane * 16, dst + c * 1024);
    }
    u64 mysup = 0, mykeep = 0;
    if (wid == 0) mysup = ~validmask[lane];
    __syncthreads();    // implicit vmcnt(0): block 0 resident

    for (int b = 0; b < 64; ++b) {
        if (wid != 0) {
            // producers: stage block b+1 into the other buffer (async)
            if (b + 1 < 64) {
                const char* src = (const char*)(mask + (size_t)(b + 1) * 4096);
                char* dst = (char*)&buf[(b & 1) ^ 1][0];
                for (int c = wid - 1; c < 32; c += 3)  // c uniform per wave
                    gload_lds16(src + c * 1024 + lane * 16, dst + c * 1024);
            }
        } else {
            // consumer (wave 0): scan 64 rows of block b from buf[b&1]
            const u64* Bp = buf[b & 1];
            int w = b;
            u32 clo = (u32)__builtin_amdgcn_readlane((int)(u32)mysup, w);
            u32 chi = (u32)__builtin_amdgcn_readlane((int)(u32)(mysup >> 32), w);
            u64 cur = ((u64)chi << 32) | clo;
            u64 blockkeep = 0;
            u64 x0, x1, x2, x3, x4, x5, x6, x7;
            u64 y0, y1, y2, y3, y4, y5, y6, y7;
            RD(x, 0)
            RD(y, 8)  PR(x, 0)
            RD(x, 16) PR(y, 8)
            RD(y, 24) PR(x, 16)
            RD(x, 32) PR(y, 24)
            RD(y, 40) PR(x, 32)
            RD(x, 48) PR(y, 40)
            RD(y, 56) PR(x, 48)
            PR(y, 56)
            if (lane == w) mykeep = blockkeep;
        }
        __syncthreads();
    }
    if (wid == 0) keep[lane] = mykeep;
}

// K8: write output [4096,5], zero suppressed rows
__global__ void k_out(const float4* __restrict__ tb, const float* __restrict__ tc,
                      const u64* __restrict__ keep, float* __restrict__ out) {
    int k = blockIdx.x * 256 + threadIdx.x;
    bool kp = (keep[k >> 6] >> (k & 63)) & 1ull;
    float4 b = tb[k];
    float c = tc[k];
    float* o = out + (size_t)k * 5;
    o[0] = kp ? b.x : 0.f;
    o[1] = kp ? b.y : 0.f;
    o[2] = kp ? b.z : 0.f;
    o[3] = kp ? b.w : 0.f;
    o[4] = kp ? c : 0.f;
}

extern "C" void kernel_launch(void* const* d_in, const int* in_sizes, int n_in,
                              void* d_out, int out_size, void* d_ws, size_t ws_size,
                              hipStream_t stream) {
    const float4* boxes = (const float4*)d_in[0];   // [1,N,4] f32
    const float*  confs = (const float*)d_in[1];    // [1,N]   f32
    float* out = (float*)d_out;                     // [4096,5] f32
    char* ws = (char*)d_ws;
    int n = in_sizes[1];

    u32* hist    = (u32*)(ws + HIST_OFF);
    int* cut     = (int*)(ws + CUT_OFF);
    u32* counter = (u32*)(ws + CNT_OFF);
    u64* comp    = (u64*)(ws + COMP_OFF);
    u64* keys    = (u64*)(ws + KEYS_OFF);
    float4* tb   = (float4*)(ws + TB_OFF);
    float*  tc   = (float*)(ws + TC_OFF);
    u64* validm  = (u64*)(ws + VALID_OFF);
    u64* keep    = (u64*)(ws + KEEP_OFF);
    u64* mask    = (u64*)(ws + MASK_OFF);

    hipMemsetAsync(ws, 0, MEMSET_BYTES, stream);
    k_keys<<<(n + 255) / 256, 256, 0, stream>>>(confs, keys, hist, n);
    k_findcut<<<1, 256, 0, stream>>>(hist, cut);
    k_compact<<<(n + 255) / 256, 256, 0, stream>>>(keys, cut, comp, counter, n);
    k_sort<<<1, 1024, 0, stream>>>(comp, boxes, tb, tc, validm);
    k_mask<<<dim3(64, 16), 256, 0, stream>>>(tb, mask);
    k_nms<<<1, 256, 0, stream>>>(mask, validm, keep);
    k_out<<<16, 256, 0, stream>>>(tb, tc, keep, out);
}

// Round 11
// 464.369 us; speedup vs baseline: 1.0112x; 1.0112x over previous
//
#include <hip/hip_runtime.h>

// ---------------- constants ----------------
#define NTOP   4096
#define SORTN  8192
#define CONF_T 0.5f
#define IOU_T  0.6f

// ws layout (bytes)
#define HIST_OFF   0          // 2048 * u32 = 8 KB
#define CUT_OFF    8192       // int
#define CNT_OFF    8196       // u32
#define COMP_OFF   16384      // 8192 * u64 = 64 KB  (zeroed)
#define MEMSET_BYTES 81920    // covers hist+cut+cnt+comp
#define KEYS_OFF   131072     // 200000 * u64 = 1.6 MB
#define TB_OFF     2097152    // 4096 * float4 = 64 KB
#define TC_OFF     2162688    // 4096 * float  = 16 KB
#define VALID_OFF  2179072    // 64 * u64
#define KEEP_OFF   2179584    // 64 * u64
#define MASK_OFF   4194304    // 4096*64*u64 = 2 MB

typedef unsigned long long u64;
typedef unsigned int u32;

// async global->LDS copy, 16B per lane per issue (1 KB per wave-instruction)
__device__ __forceinline__ void gload_lds16(const void* g, void* l) {
    __builtin_amdgcn_global_load_lds(
        (const __attribute__((address_space(1))) unsigned int*)g,
        (__attribute__((address_space(3))) unsigned int*)l, 16, 0, 0);
}

// K1: build keys + histogram of top-20 bits of score (valid only)
__global__ void k_keys(const float* __restrict__ confs, u64* __restrict__ keys,
                       u32* __restrict__ hist, int n) {
    int i = blockIdx.x * 256 + threadIdx.x;
    if (i >= n) return;
    float s = confs[i];
    if (s >= CONF_T) {
        u32 u = __float_as_uint(s);              // positive -> bits monotone
        keys[i] = ((u64)u << 32) | (u32)(~i);    // tie: lower index wins
        int bin = (int)(u >> 12) - 0x3F000;      // [0.5,1) -> [0,2047]
        bin = bin < 0 ? 0 : (bin > 2047 ? 2047 : bin);
        atomicAdd(&hist[bin], 1u);
    } else {
        keys[i] = 0ull;
    }
}

// K2: find cut bucket (largest b with suffix-count >= NTOP), single block
__global__ __launch_bounds__(256) void k_findcut(const u32* __restrict__ hist,
                                                 int* __restrict__ cut) {
    __shared__ u32 ch[256];
    int t = threadIdx.x;
    u32 h[8]; u32 s = 0;
#pragma unroll
    for (int k = 0; k < 8; ++k) { h[k] = hist[t * 8 + k]; s += h[k]; }
    ch[t] = s;
    __syncthreads();
    // inclusive suffix scan of chunk sums
    for (int off = 1; off < 256; off <<= 1) {
        u32 v = ch[t];
        u32 add = (t + off < 256) ? ch[t + off] : 0u;
        __syncthreads();
        ch[t] = v + add;
        __syncthreads();
    }
    u32 incl = ch[t];            // sum over bins >= t*8
    u32 above = incl - s;        // sum over bins >= (t+1)*8
    if (above < NTOP && incl >= NTOP) {
        u32 cum = above; int c = 0;
        for (int k = 7; k >= 0; --k) {
            cum += h[k];
            if (cum >= NTOP) { c = t * 8 + k; break; }
        }
        *cut = c;
    }
    if (t == 0 && ch[0] < NTOP) *cut = 0;   // fewer than NTOP valid: take all
}

// K3: compact candidates with bucket >= cut
__global__ void k_compact(const u64* __restrict__ keys, const int* __restrict__ cut,
                          u64* __restrict__ comp, u32* __restrict__ counter, int n) {
    int i = blockIdx.x * 256 + threadIdx.x;
    if (i >= n) return;
    u64 key = keys[i];
    if (!key) return;
    int bin = (int)(u32)(key >> 44) - 0x3F000;
    bin = bin < 0 ? 0 : (bin > 2047 ? 2047 : bin);
    if (bin >= *cut) {
        u32 p = atomicAdd(counter, 1u);
        if (p < SORTN) comp[p] = key;
    }
}

// K4: bitonic sort SORTN u64 keys descending, single block, 64KB LDS.
// Epilogue (fused, was k_gather): gather top boxes/scores, build valid bitmask.
__global__ __launch_bounds__(1024) void k_sort(const u64* __restrict__ comp,
                                               const float4* __restrict__ boxes,
                                               float4* __restrict__ tb,
                                               float* __restrict__ tc,
                                               u64* __restrict__ validmask) {
    __shared__ u64 sm[SORTN];
    int t = threadIdx.x;
    for (int i = t; i < SORTN; i += 1024) sm[i] = comp[i];
    __syncthreads();
    for (int k = 2; k <= SORTN; k <<= 1) {
        for (int j = k >> 1; j > 0; j >>= 1) {
            for (int i = t; i < SORTN; i += 1024) {
                int ixj = i ^ j;
                if (ixj > i) {
                    u64 a = sm[i], b = sm[ixj];
                    bool sw = ((i & k) == 0) ? (a < b) : (a > b);  // descending
                    if (sw) { sm[i] = b; sm[ixj] = a; }
                }
            }
            __syncthreads();
        }
    }
    // fused gather: first NTOP sorted keys -> boxes/scores/valid bitmask
    for (int base = 0; base < NTOP; base += 1024) {
        int k = base + t;
        u64 key = sm[k];
        float score = __uint_as_float((u32)(key >> 32));
        bool valid = (key != 0ull) && (score >= CONF_T);
        float4 b = make_float4(0.f, 0.f, 0.f, 0.f);
        if (valid) {
            u32 idx = ~(u32)(key & 0xFFFFFFFFull);
            b = boxes[idx];
        }
        tb[k] = b;
        tc[k] = score;
        u64 bal = __ballot(valid);
        if ((t & 63) == 0) validmask[k >> 6] = bal;
    }
}

// K6: suppression bitmask matrix: mask[row][w] bit j = iou(row, w*64+j) > T
__global__ __launch_bounds__(256) void k_mask(const float4* __restrict__ tb,
                                              u64* __restrict__ mask) {
    __shared__ float4 cb[64];
    __shared__ float  ca[64];
    int w = blockIdx.x;           // word 0..63
    int t = threadIdx.x;
    if (t < 64) {
        float4 b = tb[w * 64 + t];
        cb[t] = b;
        ca[t] = fmaxf(b.z - b.x, 0.f) * fmaxf(b.w - b.y, 0.f);
    }
    __syncthreads();
    int row = blockIdx.y * 256 + t;
    float4 rb = tb[row];
    float ra = fmaxf(rb.z - rb.x, 0.f) * fmaxf(rb.w - rb.y, 0.f);
    u64 m = 0;
#pragma unroll 8
    for (int j = 0; j < 64; ++j) {
        float4 c = cb[j];
        float lx = fmaxf(rb.x, c.x), ly = fmaxf(rb.y, c.y);
        float rx = fminf(rb.z, c.z), ry = fminf(rb.w, c.w);
        float iw = fmaxf(rx - lx, 0.f), ih = fmaxf(ry - ly, 0.f);
        float inter = iw * ih;
        float iou = inter / (ra + ca[j] - inter + 1e-9f);
        if (iou > IOU_T) m |= (1ull << j);
    }
    mask[(size_t)row * 64 + w] = m;
}

// ---- K7 consumer: software-pipelined LDS scan, schedule pinned with
// sched_barrier(0). r10 post-mortem: without pinning, hipcc sinks each
// ds_read to just before its use -> one ~120cy LDS latency PER STEP
// (measured 131 cy/step, VALUBusy 0.04%). Pipeline: 3 rotating 8-row
// register batches (x/y/z), issue batch n+2, consume batch n -> the
// compiler's in-order lgkmcnt wait finds data already resident. ----
#define SB __builtin_amdgcn_sched_barrier(0);

#define RD(p, base) \
    p##0 = Bp[(base + 0) * 64 + lane]; p##1 = Bp[(base + 1) * 64 + lane]; \
    p##2 = Bp[(base + 2) * 64 + lane]; p##3 = Bp[(base + 3) * 64 + lane]; \
    p##4 = Bp[(base + 4) * 64 + lane]; p##5 = Bp[(base + 5) * 64 + lane]; \
    p##6 = Bp[(base + 6) * 64 + lane]; p##7 = Bp[(base + 7) * 64 + lane];

#define RL64(rv) ( ((u64)(u32)__builtin_amdgcn_readlane((int)(u32)((rv) >> 32), w) << 32) \
                 |  (u64)(u32)__builtin_amdgcn_readlane((int)(u32)(rv), w) )

#define CSTEP(rv, dv, bit) { \
    bool k_ = ((cur >> (bit)) & 1ull) == 0ull; \
    u64 mm_ = k_ ? ~0ull : 0ull;        /* uniform -> s_cselect_b64 */ \
    cur |= (dv) & mm_;                  /* scalar chain */ \
    mysup |= (rv) & mm_;                /* vector accumulate */ \
    blockkeep |= k_ ? (1ull << (bit)) : 0ull; }

#define CH(p, base) { \
    u64 d0_ = RL64(p##0), d1_ = RL64(p##1), d2_ = RL64(p##2), d3_ = RL64(p##3); \
    u64 d4_ = RL64(p##4), d5_ = RL64(p##5), d6_ = RL64(p##6), d7_ = RL64(p##7); \
    CSTEP(p##0, d0_, base + 0) CSTEP(p##1, d1_, base + 1) \
    CSTEP(p##2, d2_, base + 2) CSTEP(p##3, d3_, base + 3) \
    CSTEP(p##4, d4_, base + 4) CSTEP(p##5, d5_, base + 5) \
    CSTEP(p##6, d6_, base + 6) CSTEP(p##7, d7_, base + 7) }

// K7: serial greedy NMS — producer/consumer, one 256-thread block.
// Waves 1-3: async global_load_lds staging into 2x32KB double-buffer (r10).
// Wave 0: pinned-pipeline scan (above). Bit logic unchanged (r8/r9-validated).
__global__ __launch_bounds__(256, 1) void k_nms(const u64* __restrict__ mask,
                                                const u64* __restrict__ validmask,
                                                u64* __restrict__ keep) {
    __shared__ u64 buf[2][64 * 64];     // 2 x 32 KB (one 64-row block each)
    int tid = threadIdx.x;
    int lane = tid & 63;
    int wid = tid >> 6;

    // prologue: stage block 0 into buf[0] (all 4 waves, async)
    {
        const char* src = (const char*)mask;
        char* dst = (char*)&buf[0][0];
        for (int c = wid; c < 32; c += 4)            // c uniform per wave
            gload_lds16(src + c * 1024 + lane * 16, dst + c * 1024);
    }
    u64 mysup = 0, mykeep = 0;
    if (wid == 0) mysup = ~validmask[lane];
    __syncthreads();    // implicit vmcnt(0): block 0 resident

    for (int b = 0; b < 64; ++b) {
        if (wid != 0) {
            // producers: stage block b+1 into the other buffer (async)
            if (b + 1 < 64) {
                const char* src = (const char*)(mask + (size_t)(b + 1) * 4096);
                char* dst = (char*)&buf[(b & 1) ^ 1][0];
                for (int c = wid - 1; c < 32; c += 3)  // c uniform per wave
                    gload_lds16(src + c * 1024 + lane * 16, dst + c * 1024);
            }
        } else {
            // consumer (wave 0): scan 64 rows of block b from buf[b&1]
            const u64* Bp = buf[b & 1];
            int w = b;
            u32 clo = (u32)__builtin_amdgcn_readlane((int)(u32)mysup, w);
            u32 chi = (u32)__builtin_amdgcn_readlane((int)(u32)(mysup >> 32), w);
            u64 cur = ((u64)chi << 32) | clo;
            u64 blockkeep = 0;
            u64 x0, x1, x2, x3, x4, x5, x6, x7;
            u64 y0, y1, y2, y3, y4, y5, y6, y7;
            u64 z0, z1, z2, z3, z4, z5, z6, z7;
            RD(x, 0)  RD(y, 8)  SB
            RD(z, 16) SB CH(x, 0)  SB
            RD(x, 24) SB CH(y, 8)  SB
            RD(y, 32) SB CH(z, 16) SB
            RD(z, 40) SB CH(x, 24) SB
            RD(x, 48) SB CH(y, 32) SB
            RD(y, 56) SB CH(z, 40) SB
            CH(x, 48) SB
            CH(y, 56)
            if (lane == w) mykeep = blockkeep;
        }
        __syncthreads();
    }
    if (wid == 0) keep[lane] = mykeep;
}

// K8: write output [4096,5], zero suppressed rows
__global__ void k_out(const float4* __restrict__ tb, const float* __restrict__ tc,
                      const u64* __restrict__ keep, float* __restrict__ out) {
    int k = blockIdx.x * 256 + threadIdx.x;
    bool kp = (keep[k >> 6] >> (k & 63)) & 1ull;
    float4 b = tb[k];
    float c = tc[k];
    float* o = out + (size_t)k * 5;
    o[0] = kp ? b.x : 0.f;
    o[1] = kp ? b.y : 0.f;
    o[2] = kp ? b.z : 0.f;
    o[3] = kp ? b.w : 0.f;
    o[4] = kp ? c : 0.f;
}

extern "C" void kernel_launch(void* const* d_in, const int* in_sizes, int n_in,
                              void* d_out, int out_size, void* d_ws, size_t ws_size,
                              hipStream_t stream) {
    const float4* boxes = (const float4*)d_in[0];   // [1,N,4] f32
    const float*  confs = (const float*)d_in[1];    // [1,N]   f32
    float* out = (float*)d_out;                     // [4096,5] f32
    char* ws = (char*)d_ws;
    int n = in_sizes[1];

    u32* hist    = (u32*)(ws + HIST_OFF);
    int* cut     = (int*)(ws + CUT_OFF);
    u32* counter = (u32*)(ws + CNT_OFF);
    u64* comp    = (u64*)(ws + COMP_OFF);
    u64* keys    = (u64*)(ws + KEYS_OFF);
    float4* tb   = (float4*)(ws + TB_OFF);
    float*  tc   = (float*)(ws + TC_OFF);
    u64* validm  = (u64*)(ws + VALID_OFF);
    u64* keep    = (u64*)(ws + KEEP_OFF);
    u64* mask    = (u64*)(ws + MASK_OFF);

    hipMemsetAsync(ws, 0, MEMSET_BYTES, stream);
    k_keys<<<(n + 255) / 256, 256, 0, stream>>>(confs, keys, hist, n);
    k_findcut<<<1, 256, 0, stream>>>(hist, cut);
    k_compact<<<(n + 255) / 256, 256, 0, stream>>>(keys, cut, comp, counter, n);
    k_sort<<<1, 1024, 0, stream>>>(comp, boxes, tb, tc, validm);
    k_mask<<<dim3(64, 16), 256, 0, stream>>>(tb, mask);
    k_nms<<<1, 256, 0, stream>>>(mask, validm, keep);
    k_out<<<16, 256, 0, stream>>>(tb, tc, keep, out);
}